// Round 1
// baseline (28.680 us; speedup 1.0000x reference)
//
#include <hip/hip_runtime.h>
#include <math.h>

#define SE3_EPS 1e-4f

__global__ __launch_bounds__(256) void PoseDepthUpdater_fused_kernel(
    const float* __restrict__ curr_pose,   // [B,7]
    const float* __restrict__ curr_depth,  // [B,H,W]
    const float* __restrict__ delta_pose,  // [B,6]
    const float* __restrict__ delta_depth, // [B,H,W]
    const float* __restrict__ a_p,         // [B,1]
    const float* __restrict__ a_d,         // [B,H,W]
    float* __restrict__ out_pose,          // [B,7]
    float* __restrict__ out_depth,         // [B,H,W]
    int Bn, long n)
{
    // ---------------- pose part: 32 threads in block 0 ----------------
    if (blockIdx.x == 0 && threadIdx.x < (unsigned)Bn) {
        int b = threadIdx.x;
        float ap = a_p[b];
        float v0 = ap * delta_pose[b*6+0];
        float v1 = ap * delta_pose[b*6+1];
        float v2 = ap * delta_pose[b*6+2];
        float w0 = ap * delta_pose[b*6+3];
        float w1 = ap * delta_pose[b*6+4];
        float w2 = ap * delta_pose[b*6+5];

        float theta2 = w0*w0 + w1*w1 + w2*w2;
        float theta  = sqrtf(theta2);
        bool  small  = theta < SE3_EPS;
        float safe_t  = small ? 1.0f : theta;
        float safe_t2 = small ? 1.0f : theta2;

        float s_over = small ? (0.5f - theta2 * (1.0f/48.0f))
                             : (sinf(0.5f*theta) / safe_t);
        float qx = s_over * w0, qy = s_over * w1, qz = s_over * w2;
        float qw = cosf(0.5f * theta);

        float Bc = small ? (0.5f - theta2 * (1.0f/24.0f))
                         : ((1.0f - cosf(theta)) / safe_t2);
        float Cc = small ? (1.0f/6.0f - theta2 * (1.0f/120.0f))
                         : ((theta - sinf(theta)) / (safe_t2 * safe_t));

        // wxv = cross(w, v)
        float cx = w1*v2 - w2*v1;
        float cy = w2*v0 - w0*v2;
        float cz = w0*v1 - w1*v0;
        // w x wxv
        float dx = w1*cz - w2*cy;
        float dy = w2*cx - w0*cz;
        float dz = w0*cy - w1*cx;

        float td0 = v0 + Bc*cx + Cc*dx;
        float td1 = v1 + Bc*cy + Cc*dy;
        float td2 = v2 + Bc*cz + Cc*dz;

        float tc0 = curr_pose[b*7+0], tc1 = curr_pose[b*7+1], tc2 = curr_pose[b*7+2];
        float qcx = curr_pose[b*7+3], qcy = curr_pose[b*7+4];
        float qcz = curr_pose[b*7+5], qcw = curr_pose[b*7+6];

        // qrot(q_d, t_c): u = (qx,qy,qz), scalar qw
        float uvx = qy*tc2 - qz*tc1;
        float uvy = qz*tc0 - qx*tc2;
        float uvz = qx*tc1 - qy*tc0;
        float uuvx = qy*uvz - qz*uvy;
        float uuvy = qz*uvx - qx*uvz;
        float uuvz = qx*uvy - qy*uvx;

        float tn0 = tc0 + 2.0f*(qw*uvx + uuvx) + td0;
        float tn1 = tc1 + 2.0f*(qw*uvy + uuvy) + td1;
        float tn2 = tc2 + 2.0f*(qw*uvz + uuvz) + td2;

        // qmul(q_d, q_c), xyzw Hamilton: q1 = q_d, q2 = q_c
        float nx = qw*qcx + qx*qcw + qy*qcz - qz*qcy;
        float ny = qw*qcy - qx*qcz + qy*qcw + qz*qcx;
        float nz = qw*qcz + qx*qcy - qy*qcx + qz*qcw;
        float nw = qw*qcw - qx*qcx - qy*qcy - qz*qcz;

        out_pose[b*7+0] = tn0;
        out_pose[b*7+1] = tn1;
        out_pose[b*7+2] = tn2;
        out_pose[b*7+3] = nx;
        out_pose[b*7+4] = ny;
        out_pose[b*7+5] = nz;
        out_pose[b*7+6] = nw;
    }

    // ---------------- depth part: vectorized grid-stride ----------------
    long n4 = n >> 2;
    const float4* __restrict__ c4 = (const float4*)curr_depth;
    const float4* __restrict__ d4 = (const float4*)delta_depth;
    const float4* __restrict__ a4 = (const float4*)a_d;
    float4* __restrict__ o4 = (float4*)out_depth;

    long tid    = (long)blockIdx.x * blockDim.x + threadIdx.x;
    long stride = (long)gridDim.x * blockDim.x;

    for (long i = tid; i < n4; i += stride) {
        float4 c = c4[i];
        float4 d = d4[i];
        float4 a = a4[i];
        float4 r;
        r.x = fmaxf(fmaf(a.x, d.x, c.x), 0.1f);
        r.y = fmaxf(fmaf(a.y, d.y, c.y), 0.1f);
        r.z = fmaxf(fmaf(a.z, d.z, c.z), 0.1f);
        r.w = fmaxf(fmaf(a.w, d.w, c.w), 0.1f);
        o4[i] = r;
    }

    // scalar tail (n not divisible by 4 — not hit for this shape, safety only)
    long tail_start = n4 << 2;
    for (long j = tail_start + tid; j < n; j += stride) {
        out_depth[j] = fmaxf(fmaf(a_d[j], delta_depth[j], curr_depth[j]), 0.1f);
    }
}

extern "C" void kernel_launch(void* const* d_in, const int* in_sizes, int n_in,
                              void* d_out, int out_size, void* d_ws, size_t ws_size,
                              hipStream_t stream) {
    const float* curr_pose   = (const float*)d_in[0];
    const float* curr_depth  = (const float*)d_in[1];
    const float* delta_pose  = (const float*)d_in[2];
    const float* delta_depth = (const float*)d_in[3];
    const float* a_p         = (const float*)d_in[4];
    const float* a_d         = (const float*)d_in[5];

    int  Bn = in_sizes[0] / 7;          // 32
    long n  = (long)in_sizes[1];        // B*H*W = 9,830,400

    float* out       = (float*)d_out;
    float* out_pose  = out;             // first B*7 elements
    float* out_depth = out + (long)Bn * 7;

    const int block = 256;
    long n4 = n >> 2;
    int grid = (int)((n4 + block - 1) / block);
    if (grid > 2048) grid = 2048;
    if (grid < 1) grid = 1;

    PoseDepthUpdater_fused_kernel<<<grid, block, 0, stream>>>(
        curr_pose, curr_depth, delta_pose, delta_depth, a_p, a_d,
        out_pose, out_depth, Bn, n);
}

// Round 3
// 27.880 us; speedup vs baseline: 1.0287x; 1.0287x over previous
//
#include <hip/hip_runtime.h>
#include <math.h>

#define SE3_EPS 1e-4f
#define UNROLL 4

typedef float f32x4 __attribute__((ext_vector_type(4)));

__global__ __launch_bounds__(256) void PoseDepthUpdater_fused_kernel(
    const float* __restrict__ curr_pose,   // [B,7]
    const float* __restrict__ curr_depth,  // [B,H,W]
    const float* __restrict__ delta_pose,  // [B,6]
    const float* __restrict__ delta_depth, // [B,H,W]
    const float* __restrict__ a_p,         // [B,1]
    const float* __restrict__ a_d,         // [B,H,W]
    float* __restrict__ out_pose,          // [B,7]
    float* __restrict__ out_depth,         // [B,H,W]
    int Bn, long n)
{
    // ---------------- pose part: 32 threads in block 0 ----------------
    if (blockIdx.x == 0 && threadIdx.x < (unsigned)Bn) {
        int b = threadIdx.x;
        float ap = a_p[b];
        float v0 = ap * delta_pose[b*6+0];
        float v1 = ap * delta_pose[b*6+1];
        float v2 = ap * delta_pose[b*6+2];
        float w0 = ap * delta_pose[b*6+3];
        float w1 = ap * delta_pose[b*6+4];
        float w2 = ap * delta_pose[b*6+5];

        float theta2 = w0*w0 + w1*w1 + w2*w2;
        float theta  = sqrtf(theta2);
        bool  small  = theta < SE3_EPS;
        float safe_t  = small ? 1.0f : theta;
        float safe_t2 = small ? 1.0f : theta2;

        float s_over = small ? (0.5f - theta2 * (1.0f/48.0f))
                             : (sinf(0.5f*theta) / safe_t);
        float qx = s_over * w0, qy = s_over * w1, qz = s_over * w2;
        float qw = cosf(0.5f * theta);

        float Bc = small ? (0.5f - theta2 * (1.0f/24.0f))
                         : ((1.0f - cosf(theta)) / safe_t2);
        float Cc = small ? (1.0f/6.0f - theta2 * (1.0f/120.0f))
                         : ((theta - sinf(theta)) / (safe_t2 * safe_t));

        // wxv = cross(w, v)
        float cx = w1*v2 - w2*v1;
        float cy = w2*v0 - w0*v2;
        float cz = w0*v1 - w1*v0;
        // w x wxv
        float dx = w1*cz - w2*cy;
        float dy = w2*cx - w0*cz;
        float dz = w0*cy - w1*cx;

        float td0 = v0 + Bc*cx + Cc*dx;
        float td1 = v1 + Bc*cy + Cc*dy;
        float td2 = v2 + Bc*cz + Cc*dz;

        float tc0 = curr_pose[b*7+0], tc1 = curr_pose[b*7+1], tc2 = curr_pose[b*7+2];
        float qcx = curr_pose[b*7+3], qcy = curr_pose[b*7+4];
        float qcz = curr_pose[b*7+5], qcw = curr_pose[b*7+6];

        // qrot(q_d, t_c): u = (qx,qy,qz), scalar qw
        float uvx = qy*tc2 - qz*tc1;
        float uvy = qz*tc0 - qx*tc2;
        float uvz = qx*tc1 - qy*tc0;
        float uuvx = qy*uvz - qz*uvy;
        float uuvy = qz*uvx - qx*uvz;
        float uuvz = qx*uvy - qy*uvx;

        float tn0 = tc0 + 2.0f*(qw*uvx + uuvx) + td0;
        float tn1 = tc1 + 2.0f*(qw*uvy + uuvy) + td1;
        float tn2 = tc2 + 2.0f*(qw*uvz + uuvz) + td2;

        // qmul(q_d, q_c), xyzw Hamilton: q1 = q_d, q2 = q_c
        float nx = qw*qcx + qx*qcw + qy*qcz - qz*qcy;
        float ny = qw*qcy - qx*qcz + qy*qcw + qz*qcx;
        float nz = qw*qcz + qx*qcy - qy*qcx + qz*qcw;
        float nw = qw*qcw - qx*qcx - qy*qcy - qz*qcz;

        out_pose[b*7+0] = tn0;
        out_pose[b*7+1] = tn1;
        out_pose[b*7+2] = tn2;
        out_pose[b*7+3] = nx;
        out_pose[b*7+4] = ny;
        out_pose[b*7+5] = nz;
        out_pose[b*7+6] = nw;
    }

    // ---------------- depth part: 4x unrolled, block-strided ----------------
    long n4 = n >> 2;
    const f32x4* __restrict__ c4 = (const f32x4*)curr_depth;
    const f32x4* __restrict__ d4 = (const f32x4*)delta_depth;
    const f32x4* __restrict__ a4 = (const f32x4*)a_d;
    f32x4* __restrict__ o4 = (f32x4*)out_depth;

    // block b owns float4 range [b*256*UNROLL, (b+1)*256*UNROLL)
    long base = (long)blockIdx.x * (blockDim.x * UNROLL) + threadIdx.x;

    long  idx[UNROLL];
    bool  ok[UNROLL];
    f32x4 c[UNROLL], d[UNROLL], a[UNROLL];

    #pragma unroll
    for (int k = 0; k < UNROLL; ++k) {
        idx[k] = base + (long)k * blockDim.x;
        ok[k]  = idx[k] < n4;
    }
    // issue all loads before any use: 12 independent memory ops in flight
    #pragma unroll
    for (int k = 0; k < UNROLL; ++k) if (ok[k]) c[k] = c4[idx[k]];
    #pragma unroll
    for (int k = 0; k < UNROLL; ++k) if (ok[k]) d[k] = d4[idx[k]];
    #pragma unroll
    for (int k = 0; k < UNROLL; ++k) if (ok[k]) a[k] = a4[idx[k]];

    #pragma unroll
    for (int k = 0; k < UNROLL; ++k) {
        if (ok[k]) {
            f32x4 r;
            r.x = fmaxf(fmaf(a[k].x, d[k].x, c[k].x), 0.1f);
            r.y = fmaxf(fmaf(a[k].y, d[k].y, c[k].y), 0.1f);
            r.z = fmaxf(fmaf(a[k].z, d[k].z, c[k].z), 0.1f);
            r.w = fmaxf(fmaf(a[k].w, d[k].w, c[k].w), 0.1f);
            // non-temporal: output is write-once, keep inputs resident in L3
            __builtin_nontemporal_store(r, &o4[idx[k]]);
        }
    }

    // scalar tail (n not divisible by 4 — not hit for this shape, safety only)
    long tail_start = n4 << 2;
    if (tail_start < n) {
        long tid    = (long)blockIdx.x * blockDim.x + threadIdx.x;
        long stride = (long)gridDim.x * blockDim.x;
        for (long j = tail_start + tid; j < n; j += stride) {
            out_depth[j] = fmaxf(fmaf(a_d[j], delta_depth[j], curr_depth[j]), 0.1f);
        }
    }
}

extern "C" void kernel_launch(void* const* d_in, const int* in_sizes, int n_in,
                              void* d_out, int out_size, void* d_ws, size_t ws_size,
                              hipStream_t stream) {
    const float* curr_pose   = (const float*)d_in[0];
    const float* curr_depth  = (const float*)d_in[1];
    const float* delta_pose  = (const float*)d_in[2];
    const float* delta_depth = (const float*)d_in[3];
    const float* a_p         = (const float*)d_in[4];
    const float* a_d         = (const float*)d_in[5];

    int  Bn = in_sizes[0] / 7;          // 32
    long n  = (long)in_sizes[1];        // B*H*W = 9,830,400

    float* out       = (float*)d_out;
    float* out_pose  = out;             // first B*7 elements
    float* out_depth = out + (long)Bn * 7;

    const int block = 256;
    long n4 = n >> 2;
    long per_block = (long)block * UNROLL;
    int grid = (int)((n4 + per_block - 1) / per_block);   // 2400 for this shape
    if (grid < 1) grid = 1;

    PoseDepthUpdater_fused_kernel<<<grid, block, 0, stream>>>(
        curr_pose, curr_depth, delta_pose, delta_depth, a_p, a_d,
        out_pose, out_depth, Bn, n);
}